// Round 4
// baseline (356.099 us; speedup 1.0000x reference)
//
#include <hip/hip_runtime.h>

// Problem constants: B=1, T=5, C=64, H=W=32, F=10
#define N_TOK   5120      // T*H*W
#define C_IN    64
#define F_OUT   10
#define FP      12        // padded row stride: [0..9]=data, [10..11]=unused pad

#define GRID    1024      // 4 blocks/CU x 256 CUs -> all co-resident (launch_bounds(256,4))
#define TILE    20        // rows per LDS tile in P1/P2 (== chunk length: single iter)

// ---------------------------------------------------------------------------
// Grid-wide barrier: all GRID blocks are co-resident by construction
// (__launch_bounds__(256,4) => 4 blocks/CU, grid == 4*256; LDS 2.9 KB,
// VGPR capped at 128 by the bound). Counters zeroed by hipMemsetAsync
// (captured in the graph); each counter is used exactly once per launch.
// Release/acquire: __syncthreads drains this block's stores; thread 0's
// __threadfence does the agent-scope L2 writeback before the atomic, and
// the post-spin __threadfence invalidates before readers proceed.
// ---------------------------------------------------------------------------
__device__ __forceinline__ void grid_barrier(unsigned* cnt, unsigned nblk)
{
    __syncthreads();
    if (threadIdx.x == 0) {
        __threadfence();                       // release (cross-XCD writeback)
        atomicAdd(cnt, 1u);                    // device scope by default
        while (__hip_atomic_load(cnt, __ATOMIC_RELAXED,
                                 __HIP_MEMORY_SCOPE_AGENT) < nblk)
            __builtin_amdgcn_s_sleep(2);
        __threadfence();                       // acquire (invalidate stale)
    }
    __syncthreads();
}

// ---------------------------------------------------------------------------
// One persistent kernel, 3 phases, 2 grid barriers.
// P0: blocks [0,600): qkv pointwise conv (R2 mapping, full 256 threads).
//     blocks [600,1024): zero out (51200 f) + dsum (5120 f), bounds-checked.
// P1: softmax denominators -> atomicAdd dsum. 4 mTiles x 256 n-chunks,
//     5 K-columns/thread, 20-row Q tile in LDS.
// P2: main fused pass -> atomicAdd transposed out. 4 nTiles x 256 m-chunks,
//     5 Q-rows/thread, 20-row K/V tile in LDS.
// ---------------------------------------------------------------------------
__global__ __launch_bounds__(256, 4) void fused_kernel(
    const float* __restrict__ x1, const float* __restrict__ x2,
    const float* __restrict__ aw,
    const float* __restrict__ w1, const float* __restrict__ b1,
    const float* __restrict__ w2, const float* __restrict__ b2,
    const float* __restrict__ w3, const float* __restrict__ b3,
    float* __restrict__ Q, float* __restrict__ K, float* __restrict__ V,
    float* __restrict__ dsum, float* __restrict__ out, unsigned* __restrict__ bar)
{
    const int vb  = blockIdx.x;
    const int tid = threadIdx.x;

    __shared__ __align__(16) float sq[TILE * FP];    // P1 Q tile   (960 B)
    __shared__ __align__(16) float sk[TILE * FP];    // P2 K tile   (960 B)
    __shared__ __align__(16) float sv[TILE * FP];    // P2 V tile   (960 B)
    __shared__ float siw[TILE];                      // P2 invw     (80 B)

    // ---------------- Phase 0: qkv (600 blocks) / zero init (424 blocks) ----
    if (vb < 600) {
        int arr = vb / 200;                          // 0=Q, 1=K, 2=V
        int rem = vb - arr * 200;
        int f   = rem / 20;
        int nbk = rem - f * 20;
        int n   = nbk * 256 + tid;
        int t = n >> 10, p = n & 1023;

        const float* x    = (arr == 1) ? x2 : x1;
        const float* w    = (arr == 0) ? w1 : (arr == 1) ? w2 : w3;
        const float* bias = (arr == 0) ? b1 : (arr == 1) ? b2 : b3;
        float*       dst  = (arr == 0) ? Q  : (arr == 1) ? K  : V;

        const float* xp = x + t * (C_IN * 1024) + p;
        const float* wr = w + f * C_IN;

        float4 wv[16];
#pragma unroll
        for (int i = 0; i < 16; ++i) wv[i] = ((const float4*)wr)[i];

        float acc = 0.f;
#pragma unroll
        for (int i = 0; i < 16; ++i) {
            acc = fmaf(wv[i].x, xp[(4 * i + 0) * 1024], acc);
            acc = fmaf(wv[i].y, xp[(4 * i + 1) * 1024], acc);
            acc = fmaf(wv[i].z, xp[(4 * i + 2) * 1024], acc);
            acc = fmaf(wv[i].w, xp[(4 * i + 3) * 1024], acc);
        }
        dst[n * FP + f] = acc + bias[f];
    } else {
        int z = (vb - 600) * 256 + tid;              // 424*256 = 108544 lanes
        if (z < 51200)       out[z] = 0.f;
        else if (z < 56320)  dsum[z - 51200] = 0.f;
        // z never reaches bar (separate region + 256 B guard gap)
    }

    grid_barrier(bar, GRID);

    // ---------------- Phase 1: denominators ----------------
    {
        int mTile = vb & 3;                          // 4 tiles x 1280 m
        int nc    = vb >> 2;                         // 256 chunks x 20 n
        int m0 = mTile * 1280 + tid;                 // owns m0 + c*256, c<5

        float kk[5][10];
#pragma unroll
        for (int c = 0; c < 5; ++c) {
            const float* kp = K + (m0 + c * 256) * FP;
            float4 a = ((const float4*)kp)[0];
            float4 b = ((const float4*)kp)[1];
            float2 e = ((const float2*)kp)[4];
            kk[c][0]=a.x; kk[c][1]=a.y; kk[c][2]=a.z; kk[c][3]=a.w;
            kk[c][4]=b.x; kk[c][5]=b.y; kk[c][6]=b.z; kk[c][7]=b.w;
            kk[c][8]=e.x; kk[c][9]=e.y;
        }

        if (tid < TILE * FP / 4)                     // 60 float4 = 20 Q rows
            ((float4*)sq)[tid] = ((const float4*)(Q + nc * TILE * FP))[tid];
        __syncthreads();

        float d[5] = {0.f, 0.f, 0.f, 0.f, 0.f};
#pragma unroll 2
        for (int j = 0; j < TILE; ++j) {
            const float4* qp = (const float4*)(sq + j * FP);
            float4 qa = qp[0], qb = qp[1], qc = qp[2];
            float qq[10] = {qa.x, qa.y, qa.z, qa.w, qb.x, qb.y, qb.z, qb.w,
                            qc.x, qc.y};
#pragma unroll
            for (int c = 0; c < 5; ++c) {
                float s0 = 0.f, s1 = 0.f;
#pragma unroll
                for (int f = 0; f < 5; ++f) {
                    s0 = fmaf(qq[f],     kk[c][f],     s0);
                    s1 = fmaf(qq[f + 5], kk[c][f + 5], s1);
                }
                d[c] += __expf(fminf(s0 + s1, 60.f));
            }
        }
#pragma unroll
        for (int c = 0; c < 5; ++c) atomicAdd(&dsum[m0 + c * 256], d[c]);
    }

    grid_barrier(bar + 1, GRID);

    // ---------------- Phase 2: main fused pass ----------------
    {
        int nTile = vb & 3;                          // 4 tiles x 1280 n
        int mc    = vb >> 2;                         // 256 chunks x 20 m
        int nb = nTile * 1280 + tid;                 // owns nb + r*256, r<5
        int m0 = mc * TILE;
        float w0 = aw[0], w1v = aw[1];

        float q[5][10];
#pragma unroll
        for (int r = 0; r < 5; ++r) {
            const float* qp = Q + (nb + r * 256) * FP;
            float4 a = ((const float4*)qp)[0];
            float4 b = ((const float4*)qp)[1];
            float2 e = ((const float2*)qp)[4];
            q[r][0]=a.x; q[r][1]=a.y; q[r][2]=a.z; q[r][3]=a.w;
            q[r][4]=b.x; q[r][5]=b.y; q[r][6]=b.z; q[r][7]=b.w;
            q[r][8]=e.x; q[r][9]=e.y;
        }

        if (tid < 60)
            ((float4*)sk)[tid] = ((const float4*)(K + m0 * FP))[tid];
        else if (tid >= 64 && tid < 124)
            ((float4*)sv)[tid - 64] = ((const float4*)(V + m0 * FP))[tid - 64];
        else if (tid >= 128 && tid < 128 + TILE)
            siw[tid - 128] = w0 / dsum[m0 + tid - 128];
        __syncthreads();

        float acc[5][F_OUT];
#pragma unroll
        for (int r = 0; r < 5; ++r)
#pragma unroll
            for (int f = 0; f < F_OUT; ++f) acc[r][f] = 0.f;

#pragma unroll 2
        for (int j = 0; j < TILE; ++j) {
            const float4* kp = (const float4*)(sk + j * FP);
            float4 ka = kp[0], kb = kp[1], kc = kp[2];
            float kk[10] = {ka.x, ka.y, ka.z, ka.w, kb.x, kb.y, kb.z, kb.w,
                            kc.x, kc.y};
            float iw = siw[j];
            const float4* vp = (const float4*)(sv + j * FP);
            float4 va = vp[0], vb4 = vp[1], vc = vp[2];
            float vv[10] = {va.x, va.y, va.z, va.w, vb4.x, vb4.y, vb4.z, vb4.w,
                            vc.x, vc.y};

#pragma unroll
            for (int r = 0; r < 5; ++r) {
                float s0 = 0.f, s1 = 0.f;
#pragma unroll
                for (int f = 0; f < 5; ++f) {
                    s0 = fmaf(q[r][f],     kk[f],     s0);
                    s1 = fmaf(q[r][f + 5], kk[f + 5], s1);
                }
                float s  = s0 + s1;
                float rl = fmaxf(s, 0.f);
                float e  = __expf(fminf(s, 60.f));
                float sg = e * __builtin_amdgcn_rcpf(1.f + e);
                float cf = fmaf(e, iw, fmaf(w1v, sg, w0 * rl));
#pragma unroll
                for (int f = 0; f < F_OUT; ++f) acc[r][f] = fmaf(cf, vv[f], acc[r][f]);
            }
        }

        // direct transposed accumulation into out[((t*10+f)<<10) + p]
#pragma unroll
        for (int r = 0; r < 5; ++r) {
            int n = nb + r * 256;
            int t = n >> 10, p = n & 1023;
            float* obase = out + ((t * F_OUT) << 10) + p;
#pragma unroll
            for (int f = 0; f < F_OUT; ++f)
                atomicAdd(obase + (f << 10), acc[r][f]);
        }
    }
}

// ---------------------------------------------------------------------------
extern "C" void kernel_launch(void* const* d_in, const int* in_sizes, int n_in,
                              void* d_out, int out_size, void* d_ws, size_t ws_size,
                              hipStream_t stream)
{
    const float* in1 = (const float*)d_in[0];
    const float* in2 = (const float*)d_in[1];
    const float* aw  = (const float*)d_in[2];
    const float* w1  = (const float*)d_in[3];
    const float* b1  = (const float*)d_in[4];
    const float* w2  = (const float*)d_in[5];
    const float* b2  = (const float*)d_in[6];
    const float* w3  = (const float*)d_in[7];
    const float* b3  = (const float*)d_in[8];
    float* out = (float*)d_out;

    // workspace: Q/K/V padded rows + dsum + guard gap + barrier counters
    float* ws   = (float*)d_ws;
    float* Q    = ws;                         // N*FP
    float* K    = Q + N_TOK * FP;
    float* V    = K + N_TOK * FP;
    float* dsum = V + N_TOK * FP;             // N
    unsigned* bar = (unsigned*)(dsum + N_TOK + 64);   // 256 B guard gap

    hipMemsetAsync(bar, 0, 2 * sizeof(unsigned), stream);  // graph-capturable
    fused_kernel<<<GRID, 256, 0, stream>>>(in1, in2, aw, w1, b1, w2, b2, w3, b3,
                                           Q, K, V, dsum, out, bar);
}

// Round 5
// 117.496 us; speedup vs baseline: 3.0307x; 3.0307x over previous
//
#include <hip/hip_runtime.h>

// Problem constants: B=1, T=5, C=64, H=W=32, F=10
#define N_TOK   5120      // T*H*W
#define C_IN    64
#define F_OUT   10
#define FP      12        // padded row stride: [0..9]=data, [10..11]=unused pad

#define DTILE   40        // denom: Q rows staged per LDS tile
#define MTILE   40        // main: K/V rows staged per LDS tile
#define NCHUNKS 128       // denom n-chunks  -> grid 20*128 = 2560 blocks
#define MCHUNKS 128       // main  m-chunks  -> grid 20*128 = 2560 blocks

// NOTE (R4 lesson): grid-wide single-counter barriers cost ~250 us on this
// 8-XCD chip (1024 serialized device-scope RMWs + spinners on one line);
// kernel-launch boundaries (~2-3 us) are far cheaper. Stay multi-kernel.
// Atomics are write-through to HBM (WRITE_SIZE == 4B * atomic count), so
// keep atomic counts split-invariant: dsum 655K, out 6.55M (26 MB).

// ---------------------------------------------------------------------------
// Kernel A: q/k/v pointwise conv. Thread = one (n, f, arr) output value.
// 600 blocks: arr(3) x f(10) x nblk(20). 64 coalesced loads + 64 FMA each.
// Prologue: blocks [0,200) zero out (51200 f), blocks [200,220) zero dsum.
// ---------------------------------------------------------------------------
__global__ __launch_bounds__(256) void qkv_kernel(
    const float* __restrict__ x1, const float* __restrict__ x2,
    const float* __restrict__ w1, const float* __restrict__ b1,
    const float* __restrict__ w2, const float* __restrict__ b2,
    const float* __restrict__ w3, const float* __restrict__ b3,
    float* __restrict__ Q, float* __restrict__ K, float* __restrict__ V,
    float* __restrict__ out, float* __restrict__ dsum)
{
    // zero the atomic destinations for this iteration (workspace/out are
    // re-poisoned by the harness between iterations)
    if (blockIdx.x < 200)
        out[blockIdx.x * 256 + threadIdx.x] = 0.f;
    else if (blockIdx.x < 220)
        dsum[(blockIdx.x - 200) * 256 + threadIdx.x] = 0.f;

    int arr = blockIdx.x / 200;            // 0=Q, 1=K, 2=V
    int rem = blockIdx.x - arr * 200;
    int f   = rem / 20;
    int nbk = rem - f * 20;
    int n   = nbk * 256 + threadIdx.x;
    int t = n >> 10, p = n & 1023;

    const float* x    = (arr == 1) ? x2 : x1;
    const float* w    = (arr == 0) ? w1 : (arr == 1) ? w2 : w3;
    const float* bias = (arr == 0) ? b1 : (arr == 1) ? b2 : b3;
    float*       dst  = (arr == 0) ? Q  : (arr == 1) ? K  : V;

    const float* xp = x + t * (C_IN * 1024) + p;
    const float* wr = w + f * C_IN;

    float4 wv[16];
#pragma unroll
    for (int i = 0; i < 16; ++i) wv[i] = ((const float4*)wr)[i];

    float acc = 0.f;
#pragma unroll
    for (int i = 0; i < 16; ++i) {
        acc = fmaf(wv[i].x, xp[(4 * i + 0) * 1024], acc);
        acc = fmaf(wv[i].y, xp[(4 * i + 1) * 1024], acc);
        acc = fmaf(wv[i].z, xp[(4 * i + 2) * 1024], acc);
        acc = fmaf(wv[i].w, xp[(4 * i + 3) * 1024], acc);
    }
    dst[n * FP + f] = acc + bias[f];
}

// ---------------------------------------------------------------------------
// Kernel B: softmax denominators. Thread owns ONE m-column (K in 10 regs,
// low VGPR -> high occupancy). Grid = 20 mTiles x NCHUNKS = 2560 blocks.
// dsum atomic count is split-invariant: N_TOK * NCHUNKS = 655K.
// ---------------------------------------------------------------------------
__global__ __launch_bounds__(256) void denom_kernel(
    const float* __restrict__ Q, const float* __restrict__ K,
    float* __restrict__ dsum, int nclen)
{
    int mTile = blockIdx.x % 20;
    int nc    = blockIdx.x / 20;
    int tid   = threadIdx.x;
    int m0 = mTile * 256 + tid;            // owns exactly one m

    float kk[10];
    {
        const float* kp = K + m0 * FP;
        float4 a = ((const float4*)kp)[0];
        float4 b = ((const float4*)kp)[1];
        float2 e = ((const float2*)kp)[4];
        kk[0]=a.x; kk[1]=a.y; kk[2]=a.z; kk[3]=a.w;
        kk[4]=b.x; kk[5]=b.y; kk[6]=b.z; kk[7]=b.w;
        kk[8]=e.x; kk[9]=e.y;
    }

    __shared__ __align__(16) float sq[DTILE * FP];   // 480 floats

    float d = 0.f;
    int n0 = nc * nclen;
    for (int base = n0; base < n0 + nclen; base += DTILE) {
        __syncthreads();
        if (tid < DTILE * FP / 4)   // 120 coalesced float4 loads
            ((float4*)sq)[tid] = ((const float4*)(Q + base * FP))[tid];
        __syncthreads();
#pragma unroll 4
        for (int j = 0; j < DTILE; ++j) {
            const float4* qp = (const float4*)(sq + j * FP);
            float4 qa = qp[0], qb = qp[1], qc = qp[2];
            float s0 = 0.f, s1 = 0.f;              // 2 chains: halve dep latency
            s0 = fmaf(qa.x, kk[0], s0);  s1 = fmaf(qb.y, kk[5], s1);
            s0 = fmaf(qa.y, kk[1], s0);  s1 = fmaf(qb.z, kk[6], s1);
            s0 = fmaf(qa.z, kk[2], s0);  s1 = fmaf(qb.w, kk[7], s1);
            s0 = fmaf(qa.w, kk[3], s0);  s1 = fmaf(qc.x, kk[8], s1);
            s0 = fmaf(qb.x, kk[4], s0);  s1 = fmaf(qc.y, kk[9], s1);
            d += __expf(fminf(s0 + s1, 60.f));
        }
    }
    atomicAdd(&dsum[m0], d);
}

// ---------------------------------------------------------------------------
// Kernel D: main fused pass. Thread owns ONE row n (q[10] + acc[10] regs,
// low VGPR -> high occupancy). Grid = 20 nTiles x MCHUNKS = 2560 blocks.
// Output atomic count is split-invariant: N_TOK * MCHUNKS * 10 = 6.55M.
// coef(n,m) = w0*relu(s) + w1*sigmoid(s) + exp(s)*invw[m]
// ---------------------------------------------------------------------------
__global__ __launch_bounds__(256) void main_kernel(
    const float* __restrict__ Q, const float* __restrict__ K,
    const float* __restrict__ V, const float* __restrict__ dsum,
    const float* __restrict__ aw, float* __restrict__ out, int mclen)
{
    int nTile = blockIdx.x % 20;
    int mc    = blockIdx.x / 20;
    int tid   = threadIdx.x;
    int nb = nTile * 256 + tid;            // owns exactly one row
    float w0 = aw[0], w1v = aw[1];

    float q[10];
    {
        const float* qp = Q + nb * FP;
        float4 a = ((const float4*)qp)[0];
        float4 b = ((const float4*)qp)[1];
        float2 e = ((const float2*)qp)[4];
        q[0]=a.x; q[1]=a.y; q[2]=a.z; q[3]=a.w;
        q[4]=b.x; q[5]=b.y; q[6]=b.z; q[7]=b.w;
        q[8]=e.x; q[9]=e.y;
    }

    float acc[F_OUT];
#pragma unroll
    for (int f = 0; f < F_OUT; ++f) acc[f] = 0.f;

    __shared__ __align__(16) float sk[MTILE * FP];   // 480 floats
    __shared__ __align__(16) float sv[MTILE * FP];   // 480 floats
    __shared__ float siw[MTILE];                     // invw per staged row

    int mstart = mc * mclen;
    for (int mbase = mstart; mbase < mstart + mclen; mbase += MTILE) {
        __syncthreads();
        if (tid < 120)
            ((float4*)sk)[tid] = ((const float4*)(K + mbase * FP))[tid];
        else if (tid < 240)
            ((float4*)sv)[tid - 120] = ((const float4*)(V + mbase * FP))[tid - 120];
        if (tid < MTILE)   // also stage invw (distinct LDS, pre-sync stores ok)
            siw[tid] = w0 * __builtin_amdgcn_rcpf(dsum[mbase + tid]);
        __syncthreads();

#pragma unroll 4
        for (int j = 0; j < MTILE; ++j) {
            const float4* kp = (const float4*)(sk + j * FP);
            float4 ka = kp[0], kb = kp[1], kc = kp[2];
            float iw = siw[j];

            float s0 = 0.f, s1 = 0.f;              // 2 chains: halve dep latency
            s0 = fmaf(ka.x, q[0], s0);  s1 = fmaf(kb.y, q[5], s1);
            s0 = fmaf(ka.y, q[1], s0);  s1 = fmaf(kb.z, q[6], s1);
            s0 = fmaf(ka.z, q[2], s0);  s1 = fmaf(kb.w, q[7], s1);
            s0 = fmaf(ka.w, q[3], s0);  s1 = fmaf(kc.x, q[8], s1);
            s0 = fmaf(kb.x, q[4], s0);  s1 = fmaf(kc.y, q[9], s1);
            float s  = s0 + s1;
            float rl = fmaxf(s, 0.f);
            float e  = __expf(fminf(s, 60.f));
            float sg = e * __builtin_amdgcn_rcpf(1.f + e);
            float cf = fmaf(e, iw, fmaf(w1v, sg, w0 * rl));

            const float4* vp = (const float4*)(sv + j * FP);
            float4 va = vp[0], vb4 = vp[1], vc = vp[2];
            acc[0] = fmaf(cf, va.x,  acc[0]);
            acc[1] = fmaf(cf, va.y,  acc[1]);
            acc[2] = fmaf(cf, va.z,  acc[2]);
            acc[3] = fmaf(cf, va.w,  acc[3]);
            acc[4] = fmaf(cf, vb4.x, acc[4]);
            acc[5] = fmaf(cf, vb4.y, acc[5]);
            acc[6] = fmaf(cf, vb4.z, acc[6]);
            acc[7] = fmaf(cf, vb4.w, acc[7]);
            acc[8] = fmaf(cf, vc.x,  acc[8]);
            acc[9] = fmaf(cf, vc.y,  acc[9]);
        }
    }

    // direct transposed accumulation into out[((t*10+f)<<10) + p]
    int t = nb >> 10, p = nb & 1023;
    float* obase = out + ((t * F_OUT) << 10) + p;
#pragma unroll
    for (int f = 0; f < F_OUT; ++f)
        atomicAdd(obase + (f << 10), acc[f]);
}

// ---------------------------------------------------------------------------
extern "C" void kernel_launch(void* const* d_in, const int* in_sizes, int n_in,
                              void* d_out, int out_size, void* d_ws, size_t ws_size,
                              hipStream_t stream)
{
    const float* in1 = (const float*)d_in[0];
    const float* in2 = (const float*)d_in[1];
    const float* aw  = (const float*)d_in[2];
    const float* w1  = (const float*)d_in[3];
    const float* b1  = (const float*)d_in[4];
    const float* w2  = (const float*)d_in[5];
    const float* b2  = (const float*)d_in[6];
    const float* w3  = (const float*)d_in[7];
    const float* b3  = (const float*)d_in[8];
    float* out = (float*)d_out;

    // workspace: Q/K/V padded rows + dsum (~758 KB)
    float* ws   = (float*)d_ws;
    float* Q    = ws;                        // N*FP
    float* K    = Q + N_TOK * FP;
    float* V    = K + N_TOK * FP;
    float* dsum = V + N_TOK * FP;            // N

    int nclen = N_TOK / NCHUNKS;   // 40 (== DTILE: single tile iter per block)
    int mclen = N_TOK / MCHUNKS;   // 40 (== MTILE)

    qkv_kernel<<<600, 256, 0, stream>>>(in1, in2, w1, b1, w2, b2, w3, b3,
                                        Q, K, V, out, dsum);
    denom_kernel<<<20 * NCHUNKS, 256, 0, stream>>>(Q, K, dsum, nclen);
    main_kernel<<<20 * MCHUNKS, 256, 0, stream>>>(Q, K, V, dsum, aw, out, mclen);
}